// Round 1
// baseline (215.106 us; speedup 1.0000x reference)
//
#include <hip/hip_runtime.h>
#include <math.h>

// Capsule routing, fully fused, fp32.
// x: [256][1152][8]  W: [1152][10][16][8]
// out: v [256][10][16] (40960 floats) then c_out [256][1152][10] (2949120 floats)
//
// ws layout (floats):
//   db0 @ 0        (11520)   atomic accum of sum_b a_ij, iter1
//   db1 @ 11520    (11520)   iter2
//   b1  @ 23040    (11520)
//   b2  @ 34560    (11520)
//   c2  @ 46080    (11520)
//   c3  @ 57600    (11520)
//   v1  @ 69120    (40960)
//   v2  @ 110080   (40960)
//   s_part @ 151040 (32*256*160 = 1310720)   split-K partial s slabs
// total 1461760 floats = 5.85 MB

// ---------------------------------------------------------------------------
// k_s: s_part[kb][b][n] = sum_{k in slab} x[b][k] * (c[r(k),c(n)] * W[k][n])
// grid 256 = bt(8) x kb(32); block 256 = tmg(16, TM=2 batches) x tng(16, TN=10 n)
// K-range 288 per block (36 routes), staged in 4 chunks of 72 (9 routes).
__global__ __launch_bounds__(256) void k_s(const float* __restrict__ x,
                                           const float* __restrict__ W,
                                           const float* __restrict__ cw, // [1152][10] or null (-> 1/1152)
                                           float* __restrict__ s_part)
{
    __shared__ float Ws[72 * 160];   // [kk][n]
    __shared__ float Xs[72 * 34];    // [kk][m], stride 34 pads bank conflicts
    const int bt  = blockIdx.x >> 5;
    const int kb  = blockIdx.x & 31;
    const int tid = threadIdx.x;
    const int tmg = tid & 15;        // m = tmg*2
    const int tng = tid >> 4;        // n = tng*10

    float acc[2][10];
#pragma unroll
    for (int a = 0; a < 2; ++a)
#pragma unroll
        for (int j = 0; j < 10; ++j) acc[a][j] = 0.f;

    const float inv1152 = 1.0f / 1152.0f;

    for (int chunk = 0; chunk < 4; ++chunk) {
        const int r0 = kb * 36 + chunk * 9;
        // stage W with transpose [r][c][o][i] -> [kk=(rl,i)][n=(c,o)], scaled by c_ij
        for (int idx = tid; idx < 2880; idx += 256) {
            const int h  = idx & 1;
            const int o  = (idx >> 1) & 15;
            const int c  = (idx >> 5) % 10;
            const int rl = idx / 320;
            const int r  = r0 + rl;
            const float sc = cw ? cw[r * 10 + c] : inv1152;
            const float4 w4 = *reinterpret_cast<const float4*>(&W[(((r * 10 + c) * 16 + o) * 8) + h * 4]);
            const int kkb = rl * 8 + h * 4;
            const int n = c * 16 + o;
            Ws[(kkb + 0) * 160 + n] = w4.x * sc;
            Ws[(kkb + 1) * 160 + n] = w4.y * sc;
            Ws[(kkb + 2) * 160 + n] = w4.z * sc;
            Ws[(kkb + 3) * 160 + n] = w4.w * sc;
        }
        // stage x slice [kk][m]
        for (int idx = tid; idx < 72 * 32; idx += 256) {
            const int bl = idx / 72;
            const int kk = idx % 72;
            Xs[kk * 34 + bl] = x[(bt * 32 + bl) * 9216 + kb * 288 + chunk * 72 + kk];
        }
        __syncthreads();
#pragma unroll 2
        for (int kk = 0; kk < 72; ++kk) {
            const float2 xv = *reinterpret_cast<const float2*>(&Xs[kk * 34 + tmg * 2]);
            const float* wrow = &Ws[kk * 160 + tng * 10];
#pragma unroll
            for (int j = 0; j < 10; ++j) {
                const float w = wrow[j];
                acc[0][j] += xv.x * w;
                acc[1][j] += xv.y * w;
            }
        }
        __syncthreads();
    }
    float* dst = &s_part[(kb * 256 + bt * 32 + tmg * 2) * 160 + tng * 10];
#pragma unroll
    for (int j = 0; j < 10; ++j) dst[j] = acc[0][j];
#pragma unroll
    for (int j = 0; j < 10; ++j) dst[160 + j] = acc[1][j];
}

// ---------------------------------------------------------------------------
// k_v: v[b][c][o] = squash( sum_kb s_part[kb][b][c*16+o] )
// grid 80 = bgrp(16) x cpair(5); block 256 = b_sub(16) x o(16)
__global__ __launch_bounds__(256) void k_v(const float* __restrict__ s_part,
                                           float* __restrict__ v)
{
    const int bgrp = blockIdx.x / 5;
    const int cp   = blockIdx.x % 5;
    const int b = bgrp * 16 + (threadIdx.x >> 4);
    const int o = threadIdx.x & 15;
    for (int cc = 0; cc < 2; ++cc) {
        const int c = cp * 2 + cc;
        float s = 0.f;
        const float* p = &s_part[b * 160 + c * 16 + o];
#pragma unroll 8
        for (int kbv = 0; kbv < 32; ++kbv) s += p[kbv * 40960];
        float sq = s * s;
#pragma unroll
        for (int off = 1; off < 16; off <<= 1) sq += __shfl_xor(sq, off, 16);
        const float scale = (sq / (1.f + sq)) / sqrtf(sq + 1e-9f);
        v[b * 160 + c * 16 + o] = s * scale;
    }
}

// ---------------------------------------------------------------------------
// k_a: db[r][c] += sum_b sum_o u_hat[b,r,c,o] * v[b,c,o]   (unscaled; /256 in k_sm)
// via T[m=(r,i)][n=(c,o)] = sum_b x[b][m] v[b][n], then dot with W in epilogue.
// grid 512 = mb(128, 9 routes) x nb(2, 5 caps) x bs(2, batch halves)
// block 256 (240 compute: tmg 12 x TM=6, tng 20 x TN=4)
__global__ __launch_bounds__(256) void k_a(const float* __restrict__ x,
                                           const float* __restrict__ v,
                                           const float* __restrict__ W,
                                           float* __restrict__ db)
{
    __shared__ float Xs[128 * 72];   // [bl][m]
    __shared__ float dbl[100];       // [rl][c] partials (slot 90..99 = spill guard)
    const int mb = blockIdx.x >> 2;
    const int nb = (blockIdx.x >> 1) & 1;
    const int bs = blockIdx.x & 1;
    const int tid = threadIdx.x;
    if (tid < 100) dbl[tid] = 0.f;
    for (int idx = tid; idx < 128 * 72; idx += 256) {
        const int bl = idx / 72;
        const int kk = idx % 72;
        Xs[idx] = x[(bs * 128 + bl) * 9216 + mb * 72 + kk];
    }
    __syncthreads();
    if (tid < 240) {
        const int tmg = tid / 20;
        const int tng = tid % 20;
        float acc[6][4];
#pragma unroll
        for (int a = 0; a < 6; ++a)
#pragma unroll
            for (int j = 0; j < 4; ++j) acc[a][j] = 0.f;

        const float* vp = v + (bs * 128) * 160 + nb * 80 + tng * 4;
#pragma unroll 4
        for (int bl = 0; bl < 128; ++bl) {
            const float4 vv = *reinterpret_cast<const float4*>(vp + bl * 160);
            const float* xp = &Xs[bl * 72 + tmg * 6];
#pragma unroll
            for (int mi = 0; mi < 6; ++mi) {
                const float xm = xp[mi];
                acc[mi][0] += xm * vv.x;
                acc[mi][1] += xm * vv.y;
                acc[mi][2] += xm * vv.z;
                acc[mi][3] += xm * vv.w;
            }
        }
        // epilogue: contract T-tile with W -> per-(r,c) partials
        const int n0 = nb * 80 + tng * 4;
        const int c  = n0 >> 4;
        const int o0 = n0 & 15;
        const int r0l = (tmg * 6) >> 3;
        float p0 = 0.f, p1 = 0.f;
#pragma unroll
        for (int mi = 0; mi < 6; ++mi) {
            const int ml = tmg * 6 + mi;
            const int rl = ml >> 3;
            const int i  = ml & 7;
            const int r  = mb * 9 + rl;
            const float* wp = &W[((r * 10 + c) * 16 + o0) * 8 + i];
            float t = 0.f;
#pragma unroll
            for (int ni = 0; ni < 4; ++ni) t += wp[ni * 8] * acc[mi][ni];
            if (rl == r0l) p0 += t; else p1 += t;
        }
        atomicAdd(&dbl[r0l * 10 + c], p0);
        atomicAdd(&dbl[(r0l + 1) * 10 + c], p1);   // may hit guard slots 90..99 with 0.0
    }
    __syncthreads();
    if (tid < 90) atomicAdd(&db[(mb * 9 + tid / 10) * 10 + (tid % 10)], dbl[tid]);
}

// ---------------------------------------------------------------------------
// k_sm: bnew = bprev + db/256 ; c = softmax over routes (axis 0) per cap column
// grid 10 (cap) x 128 threads, 9 routes per thread
__global__ __launch_bounds__(128) void k_sm(const float* __restrict__ bprev, // null -> 0
                                            const float* __restrict__ db,
                                            float* __restrict__ bnew,
                                            float* __restrict__ cij)
{
    __shared__ float red[2];
    __shared__ float red2[2];
    const int c = blockIdx.x;
    const int tid = threadIdx.x;
    float bv[9];
#pragma unroll
    for (int j = 0; j < 9; ++j) {
        const int idx = (tid + j * 128) * 10 + c;
        bv[j] = (bprev ? bprev[idx] : 0.f) + db[idx] * (1.0f / 256.0f);
    }
    float mx = bv[0];
#pragma unroll
    for (int j = 1; j < 9; ++j) mx = fmaxf(mx, bv[j]);
#pragma unroll
    for (int off = 1; off < 64; off <<= 1) mx = fmaxf(mx, __shfl_xor(mx, off, 64));
    if ((tid & 63) == 0) red[tid >> 6] = mx;
    __syncthreads();
    mx = fmaxf(red[0], red[1]);
    float es[9], lsum = 0.f;
#pragma unroll
    for (int j = 0; j < 9; ++j) { es[j] = expf(bv[j] - mx); lsum += es[j]; }
#pragma unroll
    for (int off = 1; off < 64; off <<= 1) lsum += __shfl_xor(lsum, off, 64);
    if ((tid & 63) == 0) red2[tid >> 6] = lsum;
    __syncthreads();
    const float inv = 1.f / (red2[0] + red2[1]);
#pragma unroll
    for (int j = 0; j < 9; ++j) {
        const int idx = (tid + j * 128) * 10 + c;
        bnew[idx] = bv[j];
        cij[idx] = es[j] * inv;
    }
}

// ---------------------------------------------------------------------------
// k_out: blocks 0..255 broadcast c3 into out[40960 + b*11520 + r*10 + c];
//        blocks 256..271 reduce+squash s_part -> out[b*160 + c*16 + o]
__global__ __launch_bounds__(256) void k_out(const float* __restrict__ s_part,
                                             const float* __restrict__ cij,
                                             float* __restrict__ out)
{
    const int tid = threadIdx.x;
    if (blockIdx.x < 256) {
        const int b = blockIdx.x;
        float* dst = &out[40960 + b * 11520];
        for (int j = tid; j < 11520; j += 256) dst[j] = cij[j];
    } else {
        const int b = (blockIdx.x - 256) * 16 + (tid >> 4);
        const int o = tid & 15;
        for (int c = 0; c < 10; ++c) {
            float s = 0.f;
            const float* p = &s_part[b * 160 + c * 16 + o];
#pragma unroll 8
            for (int kbv = 0; kbv < 32; ++kbv) s += p[kbv * 40960];
            float sq = s * s;
#pragma unroll
            for (int off = 1; off < 16; off <<= 1) sq += __shfl_xor(sq, off, 16);
            const float scale = (sq / (1.f + sq)) / sqrtf(sq + 1e-9f);
            out[b * 160 + c * 16 + o] = s * scale;
        }
    }
}

// ---------------------------------------------------------------------------
extern "C" void kernel_launch(void* const* d_in, const int* in_sizes, int n_in,
                              void* d_out, int out_size, void* d_ws, size_t ws_size,
                              hipStream_t stream)
{
    const float* x = (const float*)d_in[0];
    const float* W = (const float*)d_in[1];
    float* out = (float*)d_out;
    float* ws  = (float*)d_ws;

    float* db0 = ws;
    float* db1 = ws + 11520;
    float* b1  = ws + 23040;
    float* b2  = ws + 34560;
    float* c2  = ws + 46080;
    float* c3  = ws + 57600;
    float* v1  = ws + 69120;
    float* v2  = ws + 110080;
    float* s_part = ws + 151040;

    // atomic accumulators must start at zero every call
    hipMemsetAsync(db0, 0, 2 * 11520 * sizeof(float), stream);

    // ---- iteration 1 (c uniform = 1/1152) ----
    k_s<<<256, 256, 0, stream>>>(x, W, nullptr, s_part);
    k_v<<<80, 256, 0, stream>>>(s_part, v1);
    k_a<<<512, 256, 0, stream>>>(x, v1, W, db0);
    k_sm<<<10, 128, 0, stream>>>(nullptr, db0, b1, c2);

    // ---- iteration 2 ----
    k_s<<<256, 256, 0, stream>>>(x, W, c2, s_part);
    k_v<<<80, 256, 0, stream>>>(s_part, v2);
    k_a<<<512, 256, 0, stream>>>(x, v2, W, db1);
    k_sm<<<10, 128, 0, stream>>>(b1, db1, b2, c3);

    // ---- iteration 3 + outputs ----
    k_s<<<256, 256, 0, stream>>>(x, W, c3, s_part);
    k_out<<<272, 256, 0, stream>>>(s_part, c3, out);
}